// Round 2
// baseline (17361.766 us; speedup 1.0000x reference)
//
#include <hip/hip_runtime.h>

typedef unsigned short u16;
typedef unsigned int u32;
typedef unsigned long long u64;

typedef __bf16 bf16x8 __attribute__((ext_vector_type(8)));
typedef float f32x4 __attribute__((ext_vector_type(4)));
typedef u16 u16x4 __attribute__((ext_vector_type(4)));

#define T_DIM 8192
#define H_DIM 1024
#define IN_DIM 2048
#define FOURH 4096
#define NWG 128                       // workgroups in recurrence; 8 hidden units each
#define XW_BYTES ((u64)T_DIM * FOURH * 2)

__device__ __forceinline__ float bf2f(u16 v) { return __uint_as_float(((u32)v) << 16); }
__device__ __forceinline__ u16 f2bf(float f) {
  u32 x = __float_as_uint(f);
  return (u16)((x + 0x7fffu + ((x >> 16) & 1u)) >> 16);  // RNE
}
__device__ __forceinline__ float sigm(float x) { return 1.f / (1.f + __expf(-x)); }
__device__ __forceinline__ float tanh_f(float x) { return 1.f - 2.f / (__expf(2.f * x) + 1.f); }

// ---------------------------------------------------------------------------
// Phase 1: xW[T,4H] = x[T,IN] @ W_ih[4H,IN]^T + (b_ih + b_hh).
// fp32 inputs converted to bf16 during LDS staging; bf16 MFMA, fp32 acc,
// bf16 xW out (scratch). 128x128x32 tile, 4 waves x 4x4 16x16x32 frags.
// ---------------------------------------------------------------------------
__global__ __launch_bounds__(256) void gemm_xw(
    const float* __restrict__ A, const float* __restrict__ B,
    const float* __restrict__ b_ih, const float* __restrict__ b_hh,
    u16* __restrict__ C) {
  __shared__ u16 As[128 * 32];
  __shared__ u16 Bs[128 * 32];
  const int tid = threadIdx.x;
  const int bm = blockIdx.y * 128;
  const int bn = blockIdx.x * 128;
  const int wave = tid >> 6, lane = tid & 63;
  const int wm = (wave >> 1) * 64, wn = (wave & 1) * 64;
  const int quad = lane >> 4, l15 = lane & 15;
  f32x4 acc[4][4];
#pragma unroll
  for (int i = 0; i < 4; ++i)
#pragma unroll
    for (int j = 0; j < 4; ++j) acc[i][j] = (f32x4)(0.f);

  const int r0 = tid >> 3;        // 0..31, 4 rows per thread (stride 32)
  const int kc0 = (tid & 7) * 4;  // 4-float chunk within the 32-wide k-tile

  for (int k0 = 0; k0 < IN_DIM; k0 += 32) {
    __syncthreads();
#pragma unroll
    for (int i = 0; i < 4; ++i) {
      const int row = r0 + i * 32;
      const f32x4 av = *(const f32x4*)(A + (u64)(bm + row) * IN_DIM + k0 + kc0);
      const f32x4 bv = *(const f32x4*)(B + (u64)(bn + row) * IN_DIM + k0 + kc0);
      u16x4 ap, bp;
#pragma unroll
      for (int e = 0; e < 4; ++e) { ap[e] = f2bf(av[e]); bp[e] = f2bf(bv[e]); }
      *(u16x4*)&As[row * 32 + kc0] = ap;
      *(u16x4*)&Bs[row * 32 + kc0] = bp;
    }
    __syncthreads();
    bf16x8 af[4], bfr[4];
#pragma unroll
    for (int mi = 0; mi < 4; ++mi)
      af[mi] = *(const bf16x8*)&As[(wm + mi * 16 + l15) * 32 + quad * 8];
#pragma unroll
    for (int ni = 0; ni < 4; ++ni)
      bfr[ni] = *(const bf16x8*)&Bs[(wn + ni * 16 + l15) * 32 + quad * 8];
#pragma unroll
    for (int mi = 0; mi < 4; ++mi)
#pragma unroll
      for (int ni = 0; ni < 4; ++ni)
        acc[mi][ni] = __builtin_amdgcn_mfma_f32_16x16x32_bf16(af[mi], bfr[ni], acc[mi][ni], 0, 0, 0);
  }
  // epilogue: C/D layout col=lane&15, row=quad*4+reg (m89/m91-verified)
#pragma unroll
  for (int ni = 0; ni < 4; ++ni) {
    const int col = bn + wn + ni * 16 + l15;
    const float bias = b_ih[col] + b_hh[col];
#pragma unroll
    for (int mi = 0; mi < 4; ++mi) {
#pragma unroll
      for (int r = 0; r < 4; ++r) {
        const int row = bm + wm + mi * 16 + quad * 4 + r;
        C[(u64)row * FOURH + col] = f2bf(acc[mi][ni][r] + bias);
      }
    }
  }
}

// ---------------------------------------------------------------------------
// Phase 2: sequential LSTM. 128 persistent WGs x 256 threads, WG w owns
// hidden units [8w, 8w+8) => 32 W_hh rows held in registers (fp32, 128/thr).
// h exchanged via LLC as (gen<<32 | f32bits) relaxed agent atomics,
// double-buffered by step parity. Thread (rq=tid>>5, s=tid&31):
// rows rq*4..+3 (row r -> gate r>>3, unit r&7), k-chunk [32s, 32s+32).
// ---------------------------------------------------------------------------
__global__ __launch_bounds__(256, 1) void lstm_rec(
    const u16* __restrict__ xW, const float* __restrict__ W_hh, u64* hbuf) {
  __shared__ float h_s[32][36];   // padded: f32x4 rows spread across bank groups
  __shared__ float gsum[32];
  __shared__ float c_s[8];
  const int tid = threadIdx.x;
  const int wg = blockIdx.x;
  const int rq = tid >> 5, s = tid & 31;
  const int j0 = wg * 8;

  // load W_hh slice into registers (fp32)
  float w[4][32];
#pragma unroll
  for (int j = 0; j < 4; ++j) {
    const int r = rq * 4 + j;
    const int grow = (r >> 3) * H_DIM + j0 + (r & 7);
    const float* src = W_hh + (u64)grow * H_DIM + s * 32;
#pragma unroll
    for (int v = 0; v < 8; ++v) {
      const f32x4 ch = *(const f32x4*)(src + v * 4);
#pragma unroll
      for (int e = 0; e < 4; ++e) w[j][v * 4 + e] = ch[e];
    }
  }
  if (tid < 8) c_s[tid] = 0.f;

  float xw_cur[4] = {0.f, 0.f, 0.f, 0.f}, xw_nxt[4] = {0.f, 0.f, 0.f, 0.f};
  if (tid < 8) {
#pragma unroll
    for (int g = 0; g < 4; ++g) xw_cur[g] = bf2f(xW[(u64)g * H_DIM + j0 + tid]);
  }

  for (int t = 0; t < T_DIM; ++t) {
    // prefetch next step's xw early (independent of h)
    if (tid < 8) {
      const int tn = (t + 1 < T_DIM) ? (t + 1) : t;
#pragma unroll
      for (int g = 0; g < 4; ++g)
        xw_nxt[g] = bf2f(xW[(u64)tn * FOURH + g * H_DIM + j0 + tid]);
    }
    // stage h_t into LDS (4 elems/thread), polling the embedded generation tag
    if (t > 0) {
      u64* hb = hbuf + (u64)(t & 1) * H_DIM + tid * 4;
      u64 v0, v1, v2, v3;
      const u32 want = (u32)t;
      for (;;) {
        v0 = __hip_atomic_load(hb + 0, __ATOMIC_RELAXED, __HIP_MEMORY_SCOPE_AGENT);
        v1 = __hip_atomic_load(hb + 1, __ATOMIC_RELAXED, __HIP_MEMORY_SCOPE_AGENT);
        v2 = __hip_atomic_load(hb + 2, __ATOMIC_RELAXED, __HIP_MEMORY_SCOPE_AGENT);
        v3 = __hip_atomic_load(hb + 3, __ATOMIC_RELAXED, __HIP_MEMORY_SCOPE_AGENT);
        if ((u32)(v0 >> 32) == want && (u32)(v1 >> 32) == want &&
            (u32)(v2 >> 32) == want && (u32)(v3 >> 32) == want) break;
        __builtin_amdgcn_s_sleep(1);
      }
      f32x4 hv;
      hv[0] = __uint_as_float((u32)v0); hv[1] = __uint_as_float((u32)v1);
      hv[2] = __uint_as_float((u32)v2); hv[3] = __uint_as_float((u32)v3);
      *(f32x4*)&h_s[tid >> 3][(tid & 7) * 4] = hv;
    } else {
      *(f32x4*)&h_s[tid >> 3][(tid & 7) * 4] = (f32x4)(0.f);  // h_0 = 0
    }
    __syncthreads();

    // MAC: 4 rows x 32 k per thread, W in regs, h from LDS
    float a0 = 0.f, a1 = 0.f, a2 = 0.f, a3 = 0.f;
#pragma unroll
    for (int mg = 0; mg < 8; ++mg) {
      const f32x4 hv = *(const f32x4*)&h_s[s][mg * 4];
#pragma unroll
      for (int e = 0; e < 4; ++e) {
        const float hm = hv[e];
        const int m = mg * 4 + e;
        a0 = __builtin_fmaf(w[0][m], hm, a0);
        a1 = __builtin_fmaf(w[1][m], hm, a1);
        a2 = __builtin_fmaf(w[2][m], hm, a2);
        a3 = __builtin_fmaf(w[3][m], hm, a3);
      }
    }
    // reduce over the 32 k-chunk lanes
#pragma unroll
    for (int off = 16; off > 0; off >>= 1) {
      a0 += __shfl_down(a0, off, 32);
      a1 += __shfl_down(a1, off, 32);
      a2 += __shfl_down(a2, off, 32);
      a3 += __shfl_down(a3, off, 32);
    }
    if (s == 0) {
      gsum[rq * 4 + 0] = a0; gsum[rq * 4 + 1] = a1;
      gsum[rq * 4 + 2] = a2; gsum[rq * 4 + 3] = a3;
    }
    __syncthreads();
    // gate math + publish h_{t+1} (8 lanes of wave 0)
    if (tid < 8) {
      const int u = tid;
      const float gi = gsum[u]      + xw_cur[0];
      const float gf = gsum[8 + u]  + xw_cur[1];
      const float gg = gsum[16 + u] + xw_cur[2];
      const float go = gsum[24 + u] + xw_cur[3];
      const float iv = sigm(gi), fv = sigm(gf), gv = tanh_f(gg), ov = sigm(go);
      const float c = fv * c_s[u] + iv * gv;
      c_s[u] = c;
      const float h = ov * tanh_f(c);
      const u64 pk = ((u64)(u32)(t + 1) << 32) | (u64)__float_as_uint(h);
      __hip_atomic_store(hbuf + (u64)((t + 1) & 1) * H_DIM + j0 + u, pk,
                         __ATOMIC_RELAXED, __HIP_MEMORY_SCOPE_AGENT);
#pragma unroll
      for (int g = 0; g < 4; ++g) xw_cur[g] = xw_nxt[g];
    }
  }
}

// ---------------------------------------------------------------------------
// Phase 3: out = sigmoid(relu(h_T @ W1^T + b1) @ W2^T + b2). One block, fp32.
// h_T lives in hbuf[0] (T even), low 32 bits of each packed word.
// ---------------------------------------------------------------------------
__global__ __launch_bounds__(256) void classifier(
    const u64* __restrict__ hb, const float* __restrict__ W1, const float* __restrict__ b1,
    const float* __restrict__ W2, const float* __restrict__ b2, float* __restrict__ out) {
  __shared__ float h_s[1024];
  __shared__ float hid_s[128];
  const int tid = threadIdx.x;
#pragma unroll
  for (int i = 0; i < 4; ++i) {
    const int k = tid + i * 256;
    h_s[k] = __uint_as_float((u32)hb[k]);
  }
  __syncthreads();
  const int row = tid >> 1, sb = tid & 1;   // 2 threads per MID row
  const float* wr = W1 + (u64)row * H_DIM + sb * 512;
  float a = 0.f;
  for (int kk = 0; kk < 512; kk += 4) {
    const f32x4 ch = *(const f32x4*)(wr + kk);
#pragma unroll
    for (int e = 0; e < 4; ++e) a = __builtin_fmaf(ch[e], h_s[sb * 512 + kk + e], a);
  }
  a += __shfl_down(a, 1, 2);
  if (sb == 0) hid_s[row] = fmaxf(a + b1[row], 0.f);
  __syncthreads();
  if (tid < 64) {
    float p = hid_s[tid] * W2[tid] + hid_s[tid + 64] * W2[tid + 64];
#pragma unroll
    for (int off = 32; off > 0; off >>= 1) p += __shfl_down(p, off, 64);
    if (tid == 0) out[0] = sigm(p + b2[0]);
  }
}

extern "C" void kernel_launch(void* const* d_in, const int* in_sizes, int n_in,
                              void* d_out, int out_size, void* d_ws, size_t ws_size,
                              hipStream_t stream) {
  const float* x_seq = (const float*)d_in[0];
  const float* W_ih  = (const float*)d_in[1];
  const float* W_hh  = (const float*)d_in[2];
  const float* b_ih  = (const float*)d_in[3];
  const float* b_hh  = (const float*)d_in[4];
  const float* W1    = (const float*)d_in[5];
  const float* b1    = (const float*)d_in[6];
  const float* W2    = (const float*)d_in[7];
  const float* b2    = (const float*)d_in[8];

  u16* xW   = (u16*)d_ws;                         // 64 MB bf16 [T, 4H]
  u64* hbuf = (u64*)((char*)d_ws + XW_BYTES);     // 2 x 1024 x 8B (gen|val)

  gemm_xw<<<dim3(FOURH / 128, T_DIM / 128), 256, 0, stream>>>(x_seq, W_ih, b_ih, b_hh, xW);
  lstm_rec<<<NWG, 256, 0, stream>>>(xW, W_hh, hbuf);
  classifier<<<1, 256, 0, stream>>>(hbuf, W1, b1, W2, b2, (float*)d_out);
}